// Round 3
// baseline (877.058 us; speedup 1.0000x reference)
//
#include <hip/hip_runtime.h>

#define EPSF 1e-7f

constexpr int Bn = 4, Cn = 64, Kn = 19;
constexpr int HWn = 512 * 512;
constexpr int CHUNKS = 64;                 // chunks per image
constexpr int PIXPERBLK = HWn / CHUNKS;    // 4096 pixels per block
constexpr int THREADS = 1024;              // 16 waves
constexpr int PARTSZ = 2 * Cn * Kn;        // 2432 floats per block partial

// k_stats v2 geometry
constexpr int TILE  = 256;                 // pixels per LDS tile
constexpr int NTILE = PIXPERBLK / TILE;    // 16
constexpr int XSTR  = 260;                 // row stride (16B-aligned, pad 4)
constexpr int ACCSZ = Kn * 64;             // 1216

// ---------------- Kernel 1: per-(b,k,c) sum / sumsq / count ----------------
// lane = channel; per pixel all 64 lanes ds_add to k*64+lane (consecutive ->
// conflict-free, NO same-address atomic collisions). R2's 4-replica random-
// label scheme measured ~197 cyc/ds_add (same-address RMW serialization).
__global__ __launch_bounds__(THREADS) void k_stats(
    const float* __restrict__ x, const int* __restrict__ gt,
    float* __restrict__ part, int* __restrict__ gcnt)
{
    __shared__ float xT[2][64 * XSTR];       // 133,120 B, double-buffered tile
    __shared__ float acc[2][2][ACCSZ];       // [rep][stat][k*64+c], 19,456 B
    __shared__ int   scnt[2][Kn];

    const int tid  = threadIdx.x;
    const int lane = tid & 63;
    const int w    = tid >> 6;               // wave 0..15
    const int rep  = w & 1;

    for (int i = tid; i < 2 * 2 * ACCSZ; i += THREADS) ((float*)acc)[i] = 0.f;
    if (tid < 2 * Kn) ((int*)scnt)[tid] = 0;

    const int b    = blockIdx.x >> 6;
    const int pix0 = (blockIdx.x & 63) * PIXPERBLK;
    const float* xb  = x  + (size_t)b * Cn * HWn + pix0;
    const int*   gtb = gt + (size_t)b * HWn + pix0;

    // labels: lanes 0..15 hold the 16 pixels wave w owns in tile t
    int lab[NTILE];
    #pragma unroll
    for (int t = 0; t < NTILE; ++t) {
        int v = gtb[t * TILE + w * 16 + (lane & 15)];
        lab[t] = min(max(v, 0), Kn - 1);
    }

    // staging: thread's 4 quads q = j*1024+tid -> c = q>>6, p = (q&63)*4
    float4 r[4];
    #pragma unroll
    for (int j = 0; j < 4; ++j) {            // load tile 0
        const int q = j * THREADS + tid, c = q >> 6, p = (q & 63) << 2;
        r[j] = *reinterpret_cast<const float4*>(xb + (size_t)c * HWn + 0 * TILE + p);
    }
    #pragma unroll
    for (int j = 0; j < 4; ++j) {            // write tile 0 -> buf 0
        const int q = j * THREADS + tid, c = q >> 6, p = (q & 63) << 2;
        *reinterpret_cast<float4*>(&xT[0][c * XSTR + p]) = r[j];
    }
    #pragma unroll
    for (int j = 0; j < 4; ++j) {            // load tile 1
        const int q = j * THREADS + tid, c = q >> 6, p = (q & 63) << 2;
        r[j] = *reinterpret_cast<const float4*>(xb + (size_t)c * HWn + 1 * TILE + p);
    }

    #pragma unroll
    for (int t = 0; t < NTILE; ++t) {
        const int cur = t & 1;
        __syncthreads();                     // W(t) [prev iter] -> ACC(t); ACC(t-1) -> W(t+1)

        // accumulate tile t: lane = channel, wave w owns pixels w*16..w*16+15
        const float* xrow = &xT[cur][lane * XSTR + w * 16];
        #pragma unroll
        for (int j = 0; j < 4; ++j) {
            const float4 v = *reinterpret_cast<const float4*>(xrow + j * 4);
            const int k0 = __builtin_amdgcn_readlane(lab[t], j * 4 + 0);
            const int k1 = __builtin_amdgcn_readlane(lab[t], j * 4 + 1);
            const int k2 = __builtin_amdgcn_readlane(lab[t], j * 4 + 2);
            const int k3 = __builtin_amdgcn_readlane(lab[t], j * 4 + 3);
            atomicAdd(&acc[rep][0][k0 * 64 + lane], v.x);
            atomicAdd(&acc[rep][1][k0 * 64 + lane], v.x * v.x);
            atomicAdd(&acc[rep][0][k1 * 64 + lane], v.y);
            atomicAdd(&acc[rep][1][k1 * 64 + lane], v.y * v.y);
            atomicAdd(&acc[rep][0][k2 * 64 + lane], v.z);
            atomicAdd(&acc[rep][1][k2 * 64 + lane], v.z * v.z);
            atomicAdd(&acc[rep][0][k3 * 64 + lane], v.w);
            atomicAdd(&acc[rep][1][k3 * 64 + lane], v.w * v.w);
        }
        if (lane < 16) atomicAdd(&scnt[rep][lab[t]], 1);

        if (t + 1 < NTILE) {                 // write tile t+1 (in regs) -> other buf
            #pragma unroll
            for (int j = 0; j < 4; ++j) {
                const int q = j * THREADS + tid, c = q >> 6, p = (q & 63) << 2;
                *reinterpret_cast<float4*>(&xT[cur ^ 1][c * XSTR + p]) = r[j];
            }
        }
        if (t + 2 < NTILE) {                 // issue loads for tile t+2
            #pragma unroll
            for (int j = 0; j < 4; ++j) {
                const int q = j * THREADS + tid, c = q >> 6, p = (q & 63) << 2;
                r[j] = *reinterpret_cast<const float4*>(xb + (size_t)c * HWn + (t + 2) * TILE + p);
            }
        }
    }
    __syncthreads();

    // flush -> part in k_tables layout: i = stat*1216 + c*19 + k
    float* pb = part + (size_t)blockIdx.x * PARTSZ;
    for (int i = tid; i < PARTSZ; i += THREADS) {
        const int stat = i / (Cn * Kn), rr = i - stat * (Cn * Kn);
        const int c = rr / Kn, k = rr - c * Kn;
        pb[i] = acc[0][stat][k * 64 + c] + acc[1][stat][k * 64 + c];
    }
    if (tid < Kn) atomicAdd(&gcnt[b * Kn + tid], scnt[0][tid] + scnt[1][tid]);
}

// ---------------- Kernel 2: mean/std + mixing weights -> A,B tables ----------------
__global__ __launch_bounds__(256) void k_tables(
    const float* __restrict__ part, const int* __restrict__ gcnt,
    const float* __restrict__ aug, float* __restrict__ tabA, float* __restrict__ tabB)
{
    __shared__ float mean_s[Kn * Cn];   // [k*64 + c]
    __shared__ float std_s [Kn * Cn];
    __shared__ float wrow  [Kn * Kn];   // [t*19 + k]
    __shared__ float wsum  [Kn];
    __shared__ float validf[Kn], cntf[Kn];

    const int b = blockIdx.x, tid = threadIdx.x;

    if (tid < Kn) {
        const int cc = gcnt[b * Kn + tid];
        validf[tid] = (cc > 0) ? 1.f : 0.f;
        cntf[tid]   = (cc > 0) ? (float)cc : 1.f;
    }
    __syncthreads();

    for (int i = tid; i < Cn * Kn; i += 256) {              // i = c*19 + k
        float s = 0.f, q = 0.f;
        const float* pp = part + (size_t)b * CHUNKS * PARTSZ + i;
        for (int blk = 0; blk < CHUNKS; ++blk) {
            s += pp[(size_t)blk * PARTSZ];
            q += pp[(size_t)blk * PARTSZ + Cn * Kn];
        }
        const int c = i / Kn, k = i - c * Kn;
        const float cs  = cntf[k];
        const float m   = s / cs;
        const float var = fmaxf(q / cs - m * m, 0.f);
        mean_s[k * Cn + c] = m;
        std_s [k * Cn + c] = sqrtf(var) + EPSF;
    }
    // FIX (R1): Kn*Kn = 361 > blockDim — strided loop, not `if (tid < Kn*Kn)`.
    for (int i = tid; i < Kn * Kn; i += 256) {
        const int t = i / Kn, k = i - t * Kn;
        wrow[i] = aug[((size_t)b * Kn + t) * Kn + k] * validf[k];
    }
    __syncthreads();
    if (tid < Kn) {
        float s = 0.f;
        for (int k = 0; k < Kn; ++k) s += wrow[tid * Kn + k];
        wsum[tid] = fmaxf(s, EPSF);
    }
    __syncthreads();
    for (int i = tid; i < Kn * Cn; i += 256) {              // i = t*64 + c
        const int t = i >> 6, c = i & 63;
        const float inv = 1.f / wsum[t];
        float mm = 0.f, ms = 0.f;
        for (int k = 0; k < Kn; ++k) {
            const float wk = wrow[t * Kn + k] * inv;
            mm += wk * mean_s[k * Cn + c];
            ms += wk * std_s [k * Cn + c];
        }
        const float A  = ms / std_s[t * Cn + c];
        const float Bv = mm - mean_s[t * Cn + c] * A;
        tabA[(size_t)b * Cn * Kn + c * Kn + t] = A;   // [b][c][k] layout for K3 LDS
        tabB[(size_t)b * Cn * Kn + c * Kn + t] = Bv;
    }
}

// ---------------- Kernel 3: out = x*A[gt] + B[gt] ----------------
__global__ __launch_bounds__(THREADS) void k_apply(
    const float* __restrict__ x, const int* __restrict__ gt,
    const float* __restrict__ tabA, const float* __restrict__ tabB,
    float* __restrict__ out)
{
    __shared__ float As[Cn * Kn], Bs[Cn * Kn];   // [c*19 + k]
    const int tid   = threadIdx.x;
    const int b     = blockIdx.x >> 6;
    const int chunk = blockIdx.x & 63;

    for (int i = tid; i < Cn * Kn; i += THREADS) {
        As[i] = tabA[(size_t)b * Cn * Kn + i];
        Bs[i] = tabB[(size_t)b * Cn * Kn + i];
    }
    __syncthreads();

    const int p0 = chunk * PIXPERBLK + tid * 4;
    const int4 L = *reinterpret_cast<const int4*>(gt + (size_t)b * HWn + p0);
    const int l0 = min(max(L.x, 0), Kn - 1);
    const int l1 = min(max(L.y, 0), Kn - 1);
    const int l2 = min(max(L.z, 0), Kn - 1);
    const int l3 = min(max(L.w, 0), Kn - 1);

    const float* xp = x   + (size_t)b * Cn * HWn + p0;
    float*       op = out + (size_t)b * Cn * HWn + p0;

    #pragma unroll 16
    for (int c = 0; c < Cn; ++c) {
        const float4 v = *reinterpret_cast<const float4*>(xp + (size_t)c * HWn);
        const int co = c * Kn;
        float4 o;
        o.x = v.x * As[co + l0] + Bs[co + l0];
        o.y = v.y * As[co + l1] + Bs[co + l1];
        o.z = v.z * As[co + l2] + Bs[co + l2];
        o.w = v.w * As[co + l3] + Bs[co + l3];
        *reinterpret_cast<float4*>(op + (size_t)c * HWn) = o;
    }
}

extern "C" void kernel_launch(void* const* d_in, const int* in_sizes, int n_in,
                              void* d_out, int out_size, void* d_ws, size_t ws_size,
                              hipStream_t stream) {
    const float* x   = (const float*)d_in[0];
    const int*   gt  = (const int*)d_in[1];
    const float* aug = (const float*)d_in[2];
    float* out = (float*)d_out;

    // workspace layout (floats): partials | gcnt(int,128) | tabA | tabB
    float* part = (float*)d_ws;                                   // 256*2432
    int*   gcnt = (int*)(part + (size_t)Bn * CHUNKS * PARTSZ);
    float* tabA = (float*)(gcnt + 128);
    float* tabB = tabA + (size_t)Bn * Cn * Kn;

    hipMemsetAsync(gcnt, 0, 128 * sizeof(int), stream);
    k_stats <<<dim3(Bn * CHUNKS), dim3(THREADS), 0, stream>>>(x, gt, part, gcnt);
    k_tables<<<dim3(Bn),          dim3(256),     0, stream>>>(part, gcnt, aug, tabA, tabB);
    k_apply <<<dim3(Bn * CHUNKS), dim3(THREADS), 0, stream>>>(x, gt, tabA, tabB, out);
}

// Round 4
// 870.967 us; speedup vs baseline: 1.0070x; 1.0070x over previous
//
#include <hip/hip_runtime.h>

#define EPSF 1e-7f

constexpr int Bn = 4, Cn = 64, Kn = 19;
constexpr int HWn = 512 * 512;
constexpr int CHUNKS = 64;                 // chunks per image
constexpr int PIXPERBLK = HWn / CHUNKS;    // 4096 pixels per block
constexpr int THREADS = 1024;              // 16 waves
constexpr int PARTSZ = 2 * Cn * Kn;        // 2432 floats per block partial

// k_stats geometry
constexpr int TILE  = 256;                 // pixels per LDS tile
constexpr int NTILE = PIXPERBLK / TILE;    // 16
constexpr int XSTR  = 260;                 // row stride words (16B-aligned; b128 access is bank-balanced)
constexpr int ACCSZ = Kn * 64;             // 1216

// ---------------- Kernel 1: per-(b,k,c) sum / sumsq / count ----------------
// lane = channel; per pixel all 64 lanes ds_add to k*64+lane (consecutive).
// R3 lesson: plain atomicAdd(float*) on LDS compiles to a CAS LOOP (no
// -munsafe-fp-atomics) -> ~200 cyc/op. unsafeAtomicAdd emits native ds_add_f32.
__global__ __launch_bounds__(THREADS) void k_stats(
    const float* __restrict__ x, const int* __restrict__ gt,
    float* __restrict__ part, int* __restrict__ gcnt)
{
    __shared__ float xT[2][64 * XSTR];       // 133,120 B, double-buffered tile
    __shared__ float acc[2][2][ACCSZ];       // [rep][stat][k*64+c], 19,456 B
    __shared__ int   scnt[2][Kn];

    const int tid  = threadIdx.x;
    const int lane = tid & 63;
    const int w    = tid >> 6;               // wave 0..15
    const int rep  = w & 1;

    for (int i = tid; i < 2 * 2 * ACCSZ; i += THREADS) ((float*)acc)[i] = 0.f;
    if (tid < 2 * Kn) ((int*)scnt)[tid] = 0;

    const int b    = blockIdx.x >> 6;
    const int pix0 = (blockIdx.x & 63) * PIXPERBLK;
    const float* xb  = x  + (size_t)b * Cn * HWn + pix0;
    const int*   gtb = gt + (size_t)b * HWn + pix0;

    // labels: lanes 0..15 hold the 16 pixels wave w owns in tile t
    int lab[NTILE];
    #pragma unroll
    for (int t = 0; t < NTILE; ++t) {
        int v = gtb[t * TILE + w * 16 + (lane & 15)];
        lab[t] = min(max(v, 0), Kn - 1);
    }

    // staging: thread's 4 quads q = j*1024+tid -> c = q>>6, p = (q&63)*4
    float4 r[4];
    #pragma unroll
    for (int j = 0; j < 4; ++j) {            // load tile 0
        const int q = j * THREADS + tid, c = q >> 6, p = (q & 63) << 2;
        r[j] = *reinterpret_cast<const float4*>(xb + (size_t)c * HWn + 0 * TILE + p);
    }
    #pragma unroll
    for (int j = 0; j < 4; ++j) {            // write tile 0 -> buf 0
        const int q = j * THREADS + tid, c = q >> 6, p = (q & 63) << 2;
        *reinterpret_cast<float4*>(&xT[0][c * XSTR + p]) = r[j];
    }
    #pragma unroll
    for (int j = 0; j < 4; ++j) {            // load tile 1
        const int q = j * THREADS + tid, c = q >> 6, p = (q & 63) << 2;
        r[j] = *reinterpret_cast<const float4*>(xb + (size_t)c * HWn + 1 * TILE + p);
    }

    #pragma unroll
    for (int t = 0; t < NTILE; ++t) {
        const int cur = t & 1;
        __syncthreads();                     // W(t) [prev iter] -> ACC(t); ACC(t-1) -> W(t+1)

        // accumulate tile t: lane = channel, wave w owns pixels w*16..w*16+15
        const float* xrow = &xT[cur][lane * XSTR + w * 16];
        #pragma unroll
        for (int j = 0; j < 4; ++j) {
            const float4 v = *reinterpret_cast<const float4*>(xrow + j * 4);
            const int k0 = __builtin_amdgcn_readlane(lab[t], j * 4 + 0);
            const int k1 = __builtin_amdgcn_readlane(lab[t], j * 4 + 1);
            const int k2 = __builtin_amdgcn_readlane(lab[t], j * 4 + 2);
            const int k3 = __builtin_amdgcn_readlane(lab[t], j * 4 + 3);
            unsafeAtomicAdd(&acc[rep][0][k0 * 64 + lane], v.x);
            unsafeAtomicAdd(&acc[rep][1][k0 * 64 + lane], v.x * v.x);
            unsafeAtomicAdd(&acc[rep][0][k1 * 64 + lane], v.y);
            unsafeAtomicAdd(&acc[rep][1][k1 * 64 + lane], v.y * v.y);
            unsafeAtomicAdd(&acc[rep][0][k2 * 64 + lane], v.z);
            unsafeAtomicAdd(&acc[rep][1][k2 * 64 + lane], v.z * v.z);
            unsafeAtomicAdd(&acc[rep][0][k3 * 64 + lane], v.w);
            unsafeAtomicAdd(&acc[rep][1][k3 * 64 + lane], v.w * v.w);
        }
        if (lane < 16) atomicAdd(&scnt[rep][lab[t]], 1);   // int: native ds_add_u32

        if (t + 1 < NTILE) {                 // write tile t+1 (in regs) -> other buf
            #pragma unroll
            for (int j = 0; j < 4; ++j) {
                const int q = j * THREADS + tid, c = q >> 6, p = (q & 63) << 2;
                *reinterpret_cast<float4*>(&xT[cur ^ 1][c * XSTR + p]) = r[j];
            }
        }
        if (t + 2 < NTILE) {                 // issue loads for tile t+2
            #pragma unroll
            for (int j = 0; j < 4; ++j) {
                const int q = j * THREADS + tid, c = q >> 6, p = (q & 63) << 2;
                r[j] = *reinterpret_cast<const float4*>(xb + (size_t)c * HWn + (t + 2) * TILE + p);
            }
        }
    }
    __syncthreads();

    // flush -> part in k_tables layout: i = stat*1216 + c*19 + k
    float* pb = part + (size_t)blockIdx.x * PARTSZ;
    for (int i = tid; i < PARTSZ; i += THREADS) {
        const int stat = i / (Cn * Kn), rr = i - stat * (Cn * Kn);
        const int c = rr / Kn, k = rr - c * Kn;
        pb[i] = acc[0][stat][k * 64 + c] + acc[1][stat][k * 64 + c];
    }
    if (tid < Kn) atomicAdd(&gcnt[b * Kn + tid], scnt[0][tid] + scnt[1][tid]);
}

// ---------------- Kernel 2: mean/std + mixing weights -> AB table ----------------
__global__ __launch_bounds__(256) void k_tables(
    const float* __restrict__ part, const int* __restrict__ gcnt,
    const float* __restrict__ aug, float* __restrict__ tabAB)
{
    __shared__ float mean_s[Kn * Cn];   // [k*64 + c]
    __shared__ float std_s [Kn * Cn];
    __shared__ float wrow  [Kn * Kn];   // [t*19 + k]
    __shared__ float wsum  [Kn];
    __shared__ float validf[Kn], cntf[Kn];

    const int b = blockIdx.x, tid = threadIdx.x;

    if (tid < Kn) {
        const int cc = gcnt[b * Kn + tid];
        validf[tid] = (cc > 0) ? 1.f : 0.f;
        cntf[tid]   = (cc > 0) ? (float)cc : 1.f;
    }
    __syncthreads();

    for (int i = tid; i < Cn * Kn; i += 256) {              // i = c*19 + k
        float s = 0.f, q = 0.f;
        const float* pp = part + (size_t)b * CHUNKS * PARTSZ + i;
        for (int blk = 0; blk < CHUNKS; ++blk) {
            s += pp[(size_t)blk * PARTSZ];
            q += pp[(size_t)blk * PARTSZ + Cn * Kn];
        }
        const int c = i / Kn, k = i - c * Kn;
        const float cs  = cntf[k];
        const float m   = s / cs;
        const float var = fmaxf(q / cs - m * m, 0.f);
        mean_s[k * Cn + c] = m;
        std_s [k * Cn + c] = sqrtf(var) + EPSF;
    }
    // FIX (R1): Kn*Kn = 361 > blockDim — strided loop, not `if (tid < Kn*Kn)`.
    for (int i = tid; i < Kn * Kn; i += 256) {
        const int t = i / Kn, k = i - t * Kn;
        wrow[i] = aug[((size_t)b * Kn + t) * Kn + k] * validf[k];
    }
    __syncthreads();
    if (tid < Kn) {
        float s = 0.f;
        for (int k = 0; k < Kn; ++k) s += wrow[tid * Kn + k];
        wsum[tid] = fmaxf(s, EPSF);
    }
    __syncthreads();
    for (int i = tid; i < Kn * Cn; i += 256) {              // i = t*64 + c
        const int t = i >> 6, c = i & 63;
        const float inv = 1.f / wsum[t];
        float mm = 0.f, ms = 0.f;
        for (int k = 0; k < Kn; ++k) {
            const float wk = wrow[t * Kn + k] * inv;
            mm += wk * mean_s[k * Cn + c];
            ms += wk * std_s [k * Cn + c];
        }
        const float A  = ms / std_s[t * Cn + c];
        const float Bv = mm - mean_s[t * Cn + c] * A;
        // interleaved AB, [b][c][k][2] layout -> k_apply does one b64 read per label
        const size_t o = ((size_t)b * Cn * Kn + c * Kn + t) * 2;
        tabAB[o + 0] = A;
        tabAB[o + 1] = Bv;
    }
}

// ---------------- Kernel 3: out = x*A[gt] + B[gt] ----------------
__global__ __launch_bounds__(THREADS) void k_apply(
    const float* __restrict__ x, const int* __restrict__ gt,
    const float* __restrict__ tabAB, float* __restrict__ out)
{
    __shared__ float ABs[Cn * Kn * 2];   // [(c*19 + k)*2 + {A,B}]
    const int tid   = threadIdx.x;
    const int b     = blockIdx.x >> 6;
    const int chunk = blockIdx.x & 63;

    for (int i = tid; i < Cn * Kn * 2; i += THREADS)
        ABs[i] = tabAB[(size_t)b * Cn * Kn * 2 + i];
    __syncthreads();

    const int p0 = chunk * PIXPERBLK + tid * 4;
    const int4 L = *reinterpret_cast<const int4*>(gt + (size_t)b * HWn + p0);
    const int l0 = min(max(L.x, 0), Kn - 1);
    const int l1 = min(max(L.y, 0), Kn - 1);
    const int l2 = min(max(L.z, 0), Kn - 1);
    const int l3 = min(max(L.w, 0), Kn - 1);

    const float* xp = x   + (size_t)b * Cn * HWn + p0;
    float*       op = out + (size_t)b * Cn * HWn + p0;

    #pragma unroll 16
    for (int c = 0; c < Cn; ++c) {
        const float4 v = *reinterpret_cast<const float4*>(xp + (size_t)c * HWn);
        const int co = c * Kn;
        const float2 ab0 = *reinterpret_cast<const float2*>(&ABs[(co + l0) * 2]);
        const float2 ab1 = *reinterpret_cast<const float2*>(&ABs[(co + l1) * 2]);
        const float2 ab2 = *reinterpret_cast<const float2*>(&ABs[(co + l2) * 2]);
        const float2 ab3 = *reinterpret_cast<const float2*>(&ABs[(co + l3) * 2]);
        float4 o;
        o.x = v.x * ab0.x + ab0.y;
        o.y = v.y * ab1.x + ab1.y;
        o.z = v.z * ab2.x + ab2.y;
        o.w = v.w * ab3.x + ab3.y;
        *reinterpret_cast<float4*>(op + (size_t)c * HWn) = o;
    }
}

extern "C" void kernel_launch(void* const* d_in, const int* in_sizes, int n_in,
                              void* d_out, int out_size, void* d_ws, size_t ws_size,
                              hipStream_t stream) {
    const float* x   = (const float*)d_in[0];
    const int*   gt  = (const int*)d_in[1];
    const float* aug = (const float*)d_in[2];
    float* out = (float*)d_out;

    // workspace layout (floats): partials | gcnt(int,128) | tabAB
    float* part  = (float*)d_ws;                                  // 256*2432
    int*   gcnt  = (int*)(part + (size_t)Bn * CHUNKS * PARTSZ);
    float* tabAB = (float*)(gcnt + 128);                          // 4*64*19*2

    hipMemsetAsync(gcnt, 0, 128 * sizeof(int), stream);
    k_stats <<<dim3(Bn * CHUNKS), dim3(THREADS), 0, stream>>>(x, gt, part, gcnt);
    k_tables<<<dim3(Bn),          dim3(256),     0, stream>>>(part, gcnt, aug, tabAB);
    k_apply <<<dim3(Bn * CHUNKS), dim3(THREADS), 0, stream>>>(x, gt, tabAB, out);
}

// Round 5
// 443.990 us; speedup vs baseline: 1.9754x; 1.9617x over previous
//
#include <hip/hip_runtime.h>

#define EPSF 1e-7f

constexpr int Bn = 4, Cn = 64, Kn = 19;
constexpr int HWn = 512 * 512;
constexpr int CHUNKS = 64;                 // chunks per image
constexpr int PIXPERBLK = HWn / CHUNKS;    // 4096 pixels per block
constexpr int THREADS = 1024;              // 16 waves
constexpr int PARTSZ = 2 * Cn * Kn;        // 2432 floats per block partial

constexpr int TILE  = 256;                 // pixels per LDS tile
constexpr int NTILE = PIXPERBLK / TILE;    // 16
constexpr int PSTR  = 65;                  // [p][c] row stride (odd -> conflict-free col reads)

// ---------------- Kernel 1: per-(b,k,c) sum / sumsq / count ----------------
// R2-R4 lesson: LDS f32 atomics are ~200 cyc/wave-op on gfx950 regardless of
// address pattern (3 schemes, all ~700us). This version has ZERO LDS atomics:
// register accumulators selected by a wave-uniform scalar switch on the label.
__global__ __launch_bounds__(THREADS) void k_stats(
    const float* __restrict__ x, const int* __restrict__ gt,
    float* __restrict__ part, int* __restrict__ gcnt)
{
    __shared__ float xT[2][TILE * PSTR];     // 133,120 B; also reused as reduce scratch
    __shared__ int   scnt[16][Kn];

    const int tid  = threadIdx.x;
    const int lane = tid & 63;
    const int w    = tid >> 6;               // wave 0..15

    const int b    = blockIdx.x >> 6;
    const int pix0 = (blockIdx.x & 63) * PIXPERBLK;
    const float* xb  = x  + (size_t)b * Cn * HWn + pix0;
    const int*   gtb = gt + (size_t)b * HWn + pix0;

    // ---- labels: lanes 0..15 hold wave w's 16 pixels of tile T (16+ dup) ----
#define LLOAD(T) const int lab##T = min(max(gtb[(T) * TILE + w * 16 + (lane & 15)], 0), Kn - 1);
    LLOAD(0)  LLOAD(1)  LLOAD(2)  LLOAD(3)  LLOAD(4)  LLOAD(5)  LLOAD(6)  LLOAD(7)
    LLOAD(8)  LLOAD(9)  LLOAD(10) LLOAD(11) LLOAD(12) LLOAD(13) LLOAD(14) LLOAD(15)

    // ---- staging mapping: p2 = pixel pair, c = channel (8 per thread) ----
    const int p2    = (tid & 127) * 2;
    const int cbase = tid >> 7;
    float2 r[8];

#define LOADX(T) { _Pragma("unroll") \
    for (int j = 0; j < 8; ++j) { \
        const int c = j * 8 + cbase; \
        r[j] = *reinterpret_cast<const float2*>(xb + (size_t)c * HWn + (T) * TILE + p2); \
    } }

#define WRITEX(BUF) { _Pragma("unroll") \
    for (int j = 0; j < 8; ++j) { \
        const int c = j * 8 + cbase; \
        xT[BUF][(p2 + 0) * PSTR + c] = r[j].x; \
        xT[BUF][(p2 + 1) * PSTR + c] = r[j].y; \
    } }

    LOADX(0)

    // ---- per-wave counts via ballot (no atomics); lanes 16+ are dups -> mask ----
    {
        int cnt[Kn];
#pragma unroll
        for (int kk = 0; kk < Kn; ++kk) {
            cnt[kk] = (int)(
                __popcll(__ballot(lab0  == kk) & 0xFFFFull) + __popcll(__ballot(lab1  == kk) & 0xFFFFull) +
                __popcll(__ballot(lab2  == kk) & 0xFFFFull) + __popcll(__ballot(lab3  == kk) & 0xFFFFull) +
                __popcll(__ballot(lab4  == kk) & 0xFFFFull) + __popcll(__ballot(lab5  == kk) & 0xFFFFull) +
                __popcll(__ballot(lab6  == kk) & 0xFFFFull) + __popcll(__ballot(lab7  == kk) & 0xFFFFull) +
                __popcll(__ballot(lab8  == kk) & 0xFFFFull) + __popcll(__ballot(lab9  == kk) & 0xFFFFull) +
                __popcll(__ballot(lab10 == kk) & 0xFFFFull) + __popcll(__ballot(lab11 == kk) & 0xFFFFull) +
                __popcll(__ballot(lab12 == kk) & 0xFFFFull) + __popcll(__ballot(lab13 == kk) & 0xFFFFull) +
                __popcll(__ballot(lab14 == kk) & 0xFFFFull) + __popcll(__ballot(lab15 == kk) & 0xFFFFull));
        }
        if (lane == 0) {
#pragma unroll
            for (int kk = 0; kk < Kn; ++kk) scnt[w][kk] = cnt[kk];
        }
    }

    WRITEX(0)
    LOADX(1)

    // ---- register accumulators (all indices compile-time; stays in VGPRs) ----
    float accs[Kn], accq[Kn];
#pragma unroll
    for (int kk = 0; kk < Kn; ++kk) { accs[kk] = 0.f; accq[kk] = 0.f; }

#define KC(KK) case KK: accs[KK] += xv; accq[KK] = fmaf(xv, xv, accq[KK]); break;
#define ACCUM(T, BUF) { \
    const int pbase = (w * 16) * PSTR + lane; \
    _Pragma("unroll 1") \
    for (int i = 0; i < 16; ++i) { \
        const int k = __builtin_amdgcn_readlane(lab##T, i); \
        const float xv = xT[BUF][pbase + i * PSTR]; \
        switch (k) { \
            KC(0) KC(1) KC(2) KC(3) KC(4) KC(5) KC(6) KC(7) KC(8) KC(9) \
            KC(10) KC(11) KC(12) KC(13) KC(14) KC(15) KC(16) KC(17) KC(18) \
        } \
    } }

#define STEP(T) { \
    __syncthreads(); \
    if ((T) + 1 < NTILE) WRITEX((((T) + 1) & 1)) \
    ACCUM(T, ((T) & 1)) \
    if ((T) + 2 < NTILE) LOADX((T) + 2) \
    }

    STEP(0)  STEP(1)  STEP(2)  STEP(3)  STEP(4)  STEP(5)  STEP(6)  STEP(7)
    STEP(8)  STEP(9)  STEP(10) STEP(11) STEP(12) STEP(13) STEP(14) STEP(15)

    // ---- cross-wave reduce (non-atomic, barriered) reusing xT as scratch ----
    __syncthreads();
    float* red = &xT[0][0];                  // 8 regions x 2432 floats = 19456 <= 33280
    const int rbase = (w & 7) * PARTSZ;
    if (w >= 8) {
#pragma unroll
        for (int kk = 0; kk < Kn; ++kk) {
            red[rbase + (kk * 2 + 0) * 64 + lane] = accs[kk];
            red[rbase + (kk * 2 + 1) * 64 + lane] = accq[kk];
        }
    }
    __syncthreads();
    if (w < 8) {
#pragma unroll
        for (int kk = 0; kk < Kn; ++kk) {
            red[rbase + (kk * 2 + 0) * 64 + lane] += accs[kk];
            red[rbase + (kk * 2 + 1) * 64 + lane] += accq[kk];
        }
    }
    __syncthreads();
    for (int i = tid; i < 4 * PARTSZ; i += THREADS) red[i] += red[i + 4 * PARTSZ];
    __syncthreads();
    for (int i = tid; i < 2 * PARTSZ; i += THREADS) red[i] += red[i + 2 * PARTSZ];
    __syncthreads();
    for (int i = tid; i < 1 * PARTSZ; i += THREADS) red[i] += red[i + 1 * PARTSZ];
    __syncthreads();

    // ---- emit partials in k_tables layout: i = stat*1216 + c*19 + k ----
    float* pb = part + (size_t)blockIdx.x * PARTSZ;
    for (int i = tid; i < PARTSZ; i += THREADS) {
        const int stat = i / (Cn * Kn);
        const int rr   = i - stat * (Cn * Kn);
        const int c = rr / Kn, k = rr - c * Kn;
        pb[i] = red[(k * 2 + stat) * 64 + c];
    }
    if (tid < Kn) {
        int s = 0;
#pragma unroll
        for (int ww = 0; ww < 16; ++ww) s += scnt[ww][tid];
        atomicAdd(&gcnt[b * Kn + tid], s);   // global int atomic: native, 19/block
    }
}

// ---------------- Kernel 2: mean/std + mixing weights -> AB table ----------------
__global__ __launch_bounds__(256) void k_tables(
    const float* __restrict__ part, const int* __restrict__ gcnt,
    const float* __restrict__ aug, float* __restrict__ tabAB)
{
    __shared__ float mean_s[Kn * Cn];   // [k*64 + c]
    __shared__ float std_s [Kn * Cn];
    __shared__ float wrow  [Kn * Kn];   // [t*19 + k]
    __shared__ float wsum  [Kn];
    __shared__ float validf[Kn], cntf[Kn];

    const int b = blockIdx.x, tid = threadIdx.x;

    if (tid < Kn) {
        const int cc = gcnt[b * Kn + tid];
        validf[tid] = (cc > 0) ? 1.f : 0.f;
        cntf[tid]   = (cc > 0) ? (float)cc : 1.f;
    }
    __syncthreads();

    for (int i = tid; i < Cn * Kn; i += 256) {              // i = c*19 + k
        float s = 0.f, q = 0.f;
        const float* pp = part + (size_t)b * CHUNKS * PARTSZ + i;
        for (int blk = 0; blk < CHUNKS; ++blk) {
            s += pp[(size_t)blk * PARTSZ];
            q += pp[(size_t)blk * PARTSZ + Cn * Kn];
        }
        const int c = i / Kn, k = i - c * Kn;
        const float cs  = cntf[k];
        const float m   = s / cs;
        const float var = fmaxf(q / cs - m * m, 0.f);
        mean_s[k * Cn + c] = m;
        std_s [k * Cn + c] = sqrtf(var) + EPSF;
    }
    // FIX (R1): Kn*Kn = 361 > blockDim — strided loop, not `if (tid < Kn*Kn)`.
    for (int i = tid; i < Kn * Kn; i += 256) {
        const int t = i / Kn, k = i - t * Kn;
        wrow[i] = aug[((size_t)b * Kn + t) * Kn + k] * validf[k];
    }
    __syncthreads();
    if (tid < Kn) {
        float s = 0.f;
        for (int k = 0; k < Kn; ++k) s += wrow[tid * Kn + k];
        wsum[tid] = fmaxf(s, EPSF);
    }
    __syncthreads();
    for (int i = tid; i < Kn * Cn; i += 256) {              // i = t*64 + c
        const int t = i >> 6, c = i & 63;
        const float inv = 1.f / wsum[t];
        float mm = 0.f, ms = 0.f;
        for (int k = 0; k < Kn; ++k) {
            const float wk = wrow[t * Kn + k] * inv;
            mm += wk * mean_s[k * Cn + c];
            ms += wk * std_s [k * Cn + c];
        }
        const float A  = ms / std_s[t * Cn + c];
        const float Bv = mm - mean_s[t * Cn + c] * A;
        // interleaved AB, [b][c][k][2] layout -> k_apply does one b64 read per label
        const size_t o = ((size_t)b * Cn * Kn + c * Kn + t) * 2;
        tabAB[o + 0] = A;
        tabAB[o + 1] = Bv;
    }
}

// ---------------- Kernel 3: out = x*A[gt] + B[gt] ----------------
__global__ __launch_bounds__(THREADS) void k_apply(
    const float* __restrict__ x, const int* __restrict__ gt,
    const float* __restrict__ tabAB, float* __restrict__ out)
{
    __shared__ float ABs[Cn * Kn * 2];   // [(c*19 + k)*2 + {A,B}]
    const int tid   = threadIdx.x;
    const int b     = blockIdx.x >> 6;
    const int chunk = blockIdx.x & 63;

    for (int i = tid; i < Cn * Kn * 2; i += THREADS)
        ABs[i] = tabAB[(size_t)b * Cn * Kn * 2 + i];
    __syncthreads();

    const int p0 = chunk * PIXPERBLK + tid * 4;
    const int4 L = *reinterpret_cast<const int4*>(gt + (size_t)b * HWn + p0);
    const int l0 = min(max(L.x, 0), Kn - 1);
    const int l1 = min(max(L.y, 0), Kn - 1);
    const int l2 = min(max(L.z, 0), Kn - 1);
    const int l3 = min(max(L.w, 0), Kn - 1);

    const float* xp = x   + (size_t)b * Cn * HWn + p0;
    float*       op = out + (size_t)b * Cn * HWn + p0;

    #pragma unroll 16
    for (int c = 0; c < Cn; ++c) {
        const float4 v = *reinterpret_cast<const float4*>(xp + (size_t)c * HWn);
        const int co = c * Kn;
        const float2 ab0 = *reinterpret_cast<const float2*>(&ABs[(co + l0) * 2]);
        const float2 ab1 = *reinterpret_cast<const float2*>(&ABs[(co + l1) * 2]);
        const float2 ab2 = *reinterpret_cast<const float2*>(&ABs[(co + l2) * 2]);
        const float2 ab3 = *reinterpret_cast<const float2*>(&ABs[(co + l3) * 2]);
        float4 o;
        o.x = v.x * ab0.x + ab0.y;
        o.y = v.y * ab1.x + ab1.y;
        o.z = v.z * ab2.x + ab2.y;
        o.w = v.w * ab3.x + ab3.y;
        *reinterpret_cast<float4*>(op + (size_t)c * HWn) = o;
    }
}

extern "C" void kernel_launch(void* const* d_in, const int* in_sizes, int n_in,
                              void* d_out, int out_size, void* d_ws, size_t ws_size,
                              hipStream_t stream) {
    const float* x   = (const float*)d_in[0];
    const int*   gt  = (const int*)d_in[1];
    const float* aug = (const float*)d_in[2];
    float* out = (float*)d_out;

    // workspace layout (floats): partials | gcnt(int,128) | tabAB
    float* part  = (float*)d_ws;                                  // 256*2432
    int*   gcnt  = (int*)(part + (size_t)Bn * CHUNKS * PARTSZ);
    float* tabAB = (float*)(gcnt + 128);                          // 4*64*19*2

    hipMemsetAsync(gcnt, 0, 128 * sizeof(int), stream);
    k_stats <<<dim3(Bn * CHUNKS), dim3(THREADS), 0, stream>>>(x, gt, part, gcnt);
    k_tables<<<dim3(Bn),          dim3(256),     0, stream>>>(part, gcnt, aug, tabAB);
    k_apply <<<dim3(Bn * CHUNKS), dim3(THREADS), 0, stream>>>(x, gt, tabAB, out);
}

// Round 6
// 285.732 us; speedup vs baseline: 3.0695x; 1.5539x over previous
//
#include <hip/hip_runtime.h>

#define EPSF 1e-7f

constexpr int Bn = 4, Cn = 64, Kn = 19;
constexpr int HWn = 512 * 512;
constexpr int CHUNKS = 64;                 // chunks per image
constexpr int PIXPERBLK = HWn / CHUNKS;    // 4096 pixels per block
constexpr int THREADS = 1024;              // 16 waves
constexpr int PARTSZ = 2 * Cn * Kn;        // 2432 floats per block partial

constexpr int TILE  = 256;                 // pixels per LDS tile
constexpr int NTILE = PIXPERBLK / TILE;    // 16
constexpr int PSTR  = 65;                  // [p][c] stride (65%32==1 -> conflict-free)

// ---------------- Kernel 1: per-(b,k,c) sum / sumsq / count ----------------
// R5 lesson (rule #20): switch over acc[k] was re-rolled by the compiler into
// a runtime-indexed SCRATCH array (VGPR capped 64, 176MB HBM writes). Fix:
// 19 NAMED scalar accumulators + explicit branch tree on the wave-uniform
// label + __launch_bounds__(,4) to raise the VGPR cap to 128.
#define ALL19(M) M(0) M(1) M(2) M(3) M(4) M(5) M(6) M(7) M(8) M(9) \
                 M(10) M(11) M(12) M(13) M(14) M(15) M(16) M(17) M(18)

__global__ __launch_bounds__(THREADS, 4) void k_stats(
    const float* __restrict__ x, const int* __restrict__ gt,
    float* __restrict__ part, int* __restrict__ gcnt)
{
    __shared__ float xT[2][TILE * PSTR];     // 133,120 B; reused as reduce scratch
    __shared__ int   scnt[16][Kn];

    const int tid  = threadIdx.x;
    const int lane = tid & 63;
    const int w    = tid >> 6;               // wave 0..15

    const int b    = blockIdx.x >> 6;
    const int pix0 = (blockIdx.x & 63) * PIXPERBLK;
    const float* xb  = x  + (size_t)b * Cn * HWn + pix0;
    const int*   gtb = gt + (size_t)b * HWn + pix0;

    // staging mapping: p2 = pixel pair, cbase = channel group (8 ch/thread)
    const int p2    = (tid & 127) * 2;
    const int cbase = tid >> 7;
    float2 r[8];

#define LOADX(T) { _Pragma("unroll") \
    for (int j = 0; j < 8; ++j) { \
        const int c = j * 8 + cbase; \
        r[j] = *reinterpret_cast<const float2*>(xb + (size_t)c * HWn + (T) * TILE + p2); \
    } }

#define WRITEX(BUF) { _Pragma("unroll") \
    for (int j = 0; j < 8; ++j) { \
        const int c = j * 8 + cbase; \
        xT[BUF][(p2 + 0) * PSTR + c] = r[j].x; \
        xT[BUF][(p2 + 1) * PSTR + c] = r[j].y; \
    } }

    // 19 named accumulator triples — NOT an array, cannot be scratch-lowered.
#define DECL_(K) float s##K = 0.f, q##K = 0.f; int c##K = 0;
    ALL19(DECL_)

#define CASE_(K) { s##K += xv_; q##K = fmaf(xv_, xv_, q##K); c##K++; }
#define TREE_ { \
    if (k_ < 10) { \
      if (k_ < 5) { \
        if (k_ < 2) { if (k_ == 0) CASE_(0) else CASE_(1) } \
        else { if (k_ == 2) CASE_(2) else { if (k_ == 3) CASE_(3) else CASE_(4) } } \
      } else { \
        if (k_ < 7) { if (k_ == 5) CASE_(5) else CASE_(6) } \
        else { if (k_ == 7) CASE_(7) else { if (k_ == 8) CASE_(8) else CASE_(9) } } \
      } \
    } else { \
      if (k_ < 15) { \
        if (k_ < 12) { if (k_ == 10) CASE_(10) else CASE_(11) } \
        else { if (k_ == 12) CASE_(12) else { if (k_ == 13) CASE_(13) else CASE_(14) } } \
      } else { \
        if (k_ < 17) { if (k_ == 15) CASE_(15) else CASE_(16) } \
        else { if (k_ == 17) CASE_(17) else CASE_(18) } \
      } \
    } }

    int labC = min(max(gtb[w * 16 + (lane & 15)], 0), Kn - 1);
    int labN = 0;

    LOADX(0)
    WRITEX(0)
    LOADX(1)

    #pragma unroll 1
    for (int t = 0; t < NTILE; ++t) {
        __syncthreads();                     // buf(t&1) ready; buf(t&1^1) free
        const int bufc = t & 1;
        if (t + 1 < NTILE) {
            labN = min(max(gtb[(t + 1) * TILE + w * 16 + (lane & 15)], 0), Kn - 1);
            WRITEX(bufc ^ 1)
        }
        const int pb_ = (w * 16) * PSTR + lane;
        #pragma unroll 1
        for (int i = 0; i < 16; ++i) {       // wave w's 16 pixels of this tile
            const int   k_  = __builtin_amdgcn_readlane(labC, i);   // wave-uniform
            const float xv_ = xT[bufc][pb_ + i * PSTR];              // lane = channel
            TREE_
        }
        if (t + 2 < NTILE) LOADX(t + 2)
        labC = labN;
    }

    // per-wave counts (wave-uniform registers) -> LDS
#define SC_(K) scnt[w][K] = c##K;
    if (lane == 0) { ALL19(SC_) }

    // cross-wave reduce (non-atomic, barriered), reusing xT as scratch
    __syncthreads();
    float* red = &xT[0][0];                  // 8 regions x 2432 = 19456 <= 33280
    const int rbase = (w & 7) * PARTSZ;
#define FLW_(K) red[rbase + ((K)*2+0)*64 + lane] = s##K; red[rbase + ((K)*2+1)*64 + lane] = q##K;
#define FLA_(K) red[rbase + ((K)*2+0)*64 + lane] += s##K; red[rbase + ((K)*2+1)*64 + lane] += q##K;
    if (w >= 8) { ALL19(FLW_) }
    __syncthreads();
    if (w < 8)  { ALL19(FLA_) }
    __syncthreads();
    for (int i = tid; i < 4 * PARTSZ; i += THREADS) red[i] += red[i + 4 * PARTSZ];
    __syncthreads();
    for (int i = tid; i < 2 * PARTSZ; i += THREADS) red[i] += red[i + 2 * PARTSZ];
    __syncthreads();
    for (int i = tid; i < 1 * PARTSZ; i += THREADS) red[i] += red[i + 1 * PARTSZ];
    __syncthreads();

    // emit partials in k_tables layout: i = stat*1216 + c*19 + k
    float* pb = part + (size_t)blockIdx.x * PARTSZ;
    for (int i = tid; i < PARTSZ; i += THREADS) {
        const int stat = i / (Cn * Kn);
        const int rr   = i - stat * (Cn * Kn);
        const int c = rr / Kn, k = rr - c * Kn;
        pb[i] = red[(k * 2 + stat) * 64 + c];
    }
    if (tid < Kn) {
        int s = 0;
#pragma unroll
        for (int ww = 0; ww < 16; ++ww) s += scnt[ww][tid];
        atomicAdd(&gcnt[b * Kn + tid], s);   // global int atomic: native, 19/block
    }
}

// ---------------- Kernel 2: mean/std + mixing weights -> AB table ----------------
__global__ __launch_bounds__(256) void k_tables(
    const float* __restrict__ part, const int* __restrict__ gcnt,
    const float* __restrict__ aug, float* __restrict__ tabAB)
{
    __shared__ float mean_s[Kn * Cn];   // [k*64 + c]
    __shared__ float std_s [Kn * Cn];
    __shared__ float wrow  [Kn * Kn];   // [t*19 + k]
    __shared__ float wsum  [Kn];
    __shared__ float validf[Kn], cntf[Kn];

    const int b = blockIdx.x, tid = threadIdx.x;

    if (tid < Kn) {
        const int cc = gcnt[b * Kn + tid];
        validf[tid] = (cc > 0) ? 1.f : 0.f;
        cntf[tid]   = (cc > 0) ? (float)cc : 1.f;
    }
    __syncthreads();

    for (int i = tid; i < Cn * Kn; i += 256) {              // i = c*19 + k
        float s = 0.f, q = 0.f;
        const float* pp = part + (size_t)b * CHUNKS * PARTSZ + i;
        for (int blk = 0; blk < CHUNKS; ++blk) {
            s += pp[(size_t)blk * PARTSZ];
            q += pp[(size_t)blk * PARTSZ + Cn * Kn];
        }
        const int c = i / Kn, k = i - c * Kn;
        const float cs  = cntf[k];
        const float m   = s / cs;
        const float var = fmaxf(q / cs - m * m, 0.f);
        mean_s[k * Cn + c] = m;
        std_s [k * Cn + c] = sqrtf(var) + EPSF;
    }
    // FIX (R1): Kn*Kn = 361 > blockDim — strided loop, not `if (tid < Kn*Kn)`.
    for (int i = tid; i < Kn * Kn; i += 256) {
        const int t = i / Kn, k = i - t * Kn;
        wrow[i] = aug[((size_t)b * Kn + t) * Kn + k] * validf[k];
    }
    __syncthreads();
    if (tid < Kn) {
        float s = 0.f;
        for (int k = 0; k < Kn; ++k) s += wrow[tid * Kn + k];
        wsum[tid] = fmaxf(s, EPSF);
    }
    __syncthreads();
    for (int i = tid; i < Kn * Cn; i += 256) {              // i = t*64 + c
        const int t = i >> 6, c = i & 63;
        const float inv = 1.f / wsum[t];
        float mm = 0.f, ms = 0.f;
        for (int k = 0; k < Kn; ++k) {
            const float wk = wrow[t * Kn + k] * inv;
            mm += wk * mean_s[k * Cn + c];
            ms += wk * std_s [k * Cn + c];
        }
        const float A  = ms / std_s[t * Cn + c];
        const float Bv = mm - mean_s[t * Cn + c] * A;
        // interleaved AB, [b][c][k][2] layout -> k_apply does one b64 read per label
        const size_t o = ((size_t)b * Cn * Kn + c * Kn + t) * 2;
        tabAB[o + 0] = A;
        tabAB[o + 1] = Bv;
    }
}

// ---------------- Kernel 3: out = x*A[gt] + B[gt] ----------------
__global__ __launch_bounds__(THREADS) void k_apply(
    const float* __restrict__ x, const int* __restrict__ gt,
    const float* __restrict__ tabAB, float* __restrict__ out)
{
    __shared__ float ABs[Cn * Kn * 2];   // [(c*19 + k)*2 + {A,B}]
    const int tid   = threadIdx.x;
    const int b     = blockIdx.x >> 6;
    const int chunk = blockIdx.x & 63;

    for (int i = tid; i < Cn * Kn * 2; i += THREADS)
        ABs[i] = tabAB[(size_t)b * Cn * Kn * 2 + i];
    __syncthreads();

    const int p0 = chunk * PIXPERBLK + tid * 4;
    const int4 L = *reinterpret_cast<const int4*>(gt + (size_t)b * HWn + p0);
    const int l0 = min(max(L.x, 0), Kn - 1);
    const int l1 = min(max(L.y, 0), Kn - 1);
    const int l2 = min(max(L.z, 0), Kn - 1);
    const int l3 = min(max(L.w, 0), Kn - 1);

    const float* xp = x   + (size_t)b * Cn * HWn + p0;
    float*       op = out + (size_t)b * Cn * HWn + p0;

    #pragma unroll 16
    for (int c = 0; c < Cn; ++c) {
        const float4 v = *reinterpret_cast<const float4*>(xp + (size_t)c * HWn);
        const int co = c * Kn;
        const float2 ab0 = *reinterpret_cast<const float2*>(&ABs[(co + l0) * 2]);
        const float2 ab1 = *reinterpret_cast<const float2*>(&ABs[(co + l1) * 2]);
        const float2 ab2 = *reinterpret_cast<const float2*>(&ABs[(co + l2) * 2]);
        const float2 ab3 = *reinterpret_cast<const float2*>(&ABs[(co + l3) * 2]);
        float4 o;
        o.x = v.x * ab0.x + ab0.y;
        o.y = v.y * ab1.x + ab1.y;
        o.z = v.z * ab2.x + ab2.y;
        o.w = v.w * ab3.x + ab3.y;
        *reinterpret_cast<float4*>(op + (size_t)c * HWn) = o;
    }
}

extern "C" void kernel_launch(void* const* d_in, const int* in_sizes, int n_in,
                              void* d_out, int out_size, void* d_ws, size_t ws_size,
                              hipStream_t stream) {
    const float* x   = (const float*)d_in[0];
    const int*   gt  = (const int*)d_in[1];
    const float* aug = (const float*)d_in[2];
    float* out = (float*)d_out;

    // workspace layout (floats): partials | gcnt(int,128) | tabAB
    float* part  = (float*)d_ws;                                  // 256*2432
    int*   gcnt  = (int*)(part + (size_t)Bn * CHUNKS * PARTSZ);
    float* tabAB = (float*)(gcnt + 128);                          // 4*64*19*2

    hipMemsetAsync(gcnt, 0, 128 * sizeof(int), stream);
    k_stats <<<dim3(Bn * CHUNKS), dim3(THREADS), 0, stream>>>(x, gt, part, gcnt);
    k_tables<<<dim3(Bn),          dim3(256),     0, stream>>>(part, gcnt, aug, tabAB);
    k_apply <<<dim3(Bn * CHUNKS), dim3(THREADS), 0, stream>>>(x, gt, tabAB, out);
}